// Round 5
// baseline (1039.377 us; speedup 1.0000x reference)
//
#include <hip/hip_runtime.h>
#include <math.h>

#define H 256
#define HEADS 4
#define BM 128
#define BK 32
#define TM 16
#define TN 8
#define S_SPLIT 4

// ---------------------------------------------------------------------------
// Kernel 1: scores[N,4] = tanh(x @ W1 + b1) @ W2   (fp32 vector-ALU path)
// Block: 256 thr = tx(32 col-groups) x ty(8 row-groups); thread = 16x8 tile.
// sX: XOR-swizzled float4 layout -> conflict-free staging writes (2/bank)
// and xr loads as 4x ds_read_b128 (2-addr broadcast). Bank math:
//   write instr (fixed j): bank = ((r>>2 ^ kq>>2)*4 + (r&3)) covers 32 banks
//   exactly 2 lanes each; read b128 has 2 unique addrs/wave (free).
// ---------------------------------------------------------------------------
__global__ __launch_bounds__(256, 2)
void scores_kernel(const float* __restrict__ x, const float* __restrict__ W1,
                   const float* __restrict__ b1, const float* __restrict__ W2,
                   float* __restrict__ scores, int N)
{
    __shared__ float sX[BK * BM];     // swizzled: [k][cg^swz(k)][e]
    __shared__ float sW[BK][H];       // W1 tile: sW[k][c]

    const int tid = threadIdx.x;
    const int tx = tid & 31;
    const int ty = tid >> 5;
    const int row0 = blockIdx.x * BM;

    float acc[TM][TN];
    #pragma unroll
    for (int r = 0; r < TM; ++r)
        #pragma unroll
        for (int c = 0; c < TN; ++c) acc[r][c] = 0.f;

    for (int k0 = 0; k0 < H; k0 += BK) {
        // stage x tile (128 rows x 32 k): 1024 float4, 4/thread, swizzled write
        #pragma unroll
        for (int it = 0; it < 4; ++it) {
            int f  = it * 256 + tid;
            int r  = f >> 3;              // 0..127
            int kq = (f & 7) * 4;         // 0,4,..,28
            int row = row0 + r;
            float4 v = make_float4(0.f, 0.f, 0.f, 0.f);
            if (row < N) v = *(const float4*)(x + (size_t)row * H + k0 + kq);
            int cg = (r >> 2) ^ ((kq >> 2) & 7);     // (kq+j)>>2 == kq>>2 for j<4
            int base = cg * 4 + (r & 3);
            sX[(kq + 0) * BM + base] = v.x;
            sX[(kq + 1) * BM + base] = v.y;
            sX[(kq + 2) * BM + base] = v.z;
            sX[(kq + 3) * BM + base] = v.w;
        }
        // stage W1 tile (32 k-rows x 256 cols): 2048 float4, 8/thread
        #pragma unroll
        for (int it = 0; it < 8; ++it) {
            int f  = it * 256 + tid;
            int k  = f >> 6;
            int c4 = (f & 63) * 4;
            *(float4*)(&sW[k][c4]) = *(const float4*)(W1 + (size_t)(k0 + k) * H + c4);
        }
        __syncthreads();

        const float4* sX4 = (const float4*)sX;
        const int ty4 = ty * 4;
        #pragma unroll
        for (int k = 0; k < BK; ++k) {
            const int swz = (k >> 2) & 7;
            float4 xq[4];
            #pragma unroll
            for (int q = 0; q < 4; ++q)
                xq[q] = sX4[k * (BM / 4) + ((ty4 + q) ^ swz)];   // rows ty*16+q*4..+3
            float wc[TN];
            #pragma unroll
            for (int c = 0; c < TN; ++c) wc[c] = sW[k][tx * TN + c];  // 2x b128
            #pragma unroll
            for (int q = 0; q < 4; ++q) {
                acc[q * 4 + 0][0] = fmaf(xq[q].x, wc[0], acc[q * 4 + 0][0]);
                #pragma unroll
                for (int c = 0; c < TN; ++c) {
                    acc[q * 4 + 0][c] = (c == 0) ? acc[q * 4 + 0][c]
                                                 : fmaf(xq[q].x, wc[c], acc[q * 4 + 0][c]);
                    acc[q * 4 + 1][c] = fmaf(xq[q].y, wc[c], acc[q * 4 + 1][c]);
                    acc[q * 4 + 2][c] = fmaf(xq[q].z, wc[c], acc[q * 4 + 2][c]);
                    acc[q * 4 + 3][c] = fmaf(xq[q].w, wc[c], acc[q * 4 + 3][c]);
                }
            }
        }
        __syncthreads();
    }

    // epilogue: h = tanh(acc + b1[col]); ps[r][head] += h * W2[col][head]
    float ps[TM][HEADS];
    #pragma unroll
    for (int r = 0; r < TM; ++r)
        #pragma unroll
        for (int hh = 0; hh < HEADS; ++hh) ps[r][hh] = 0.f;

    #pragma unroll
    for (int c = 0; c < TN; ++c) {
        int col = tx * TN + c;
        float bb = b1[col];
        float4 w2 = *(const float4*)(W2 + (size_t)col * HEADS);
        #pragma unroll
        for (int r = 0; r < TM; ++r) {
            float hv = tanhf(acc[r][c] + bb);
            ps[r][0] = fmaf(hv, w2.x, ps[r][0]);
            ps[r][1] = fmaf(hv, w2.y, ps[r][1]);
            ps[r][2] = fmaf(hv, w2.z, ps[r][2]);
            ps[r][3] = fmaf(hv, w2.w, ps[r][3]);
        }
    }
    // reduce across tx (xor<32 stays within each 32-lane half-wave)
    #pragma unroll
    for (int m = 16; m >= 1; m >>= 1) {
        #pragma unroll
        for (int r = 0; r < TM; ++r)
            #pragma unroll
            for (int hh = 0; hh < HEADS; ++hh)
                ps[r][hh] += __shfl_xor(ps[r][hh], m, 64);
    }
    if (tx == 0) {
        #pragma unroll
        for (int r = 0; r < TM; ++r) {
            int row = row0 + ty * TM + r;
            if (row < N) {
                float4 o = make_float4(ps[r][0], ps[r][1], ps[r][2], ps[r][3]);
                *(float4*)(scores + (size_t)row * HEADS) = o;   // 16B-aligned
            }
        }
    }
}

// ---------------------------------------------------------------------------
// Block-wide float4 reductions (max / sum) for 256-thread blocks.
// ---------------------------------------------------------------------------
__device__ inline float4 blockMax4(float4 v, float4* lds) {
    #pragma unroll
    for (int m = 32; m >= 1; m >>= 1) {
        v.x = fmaxf(v.x, __shfl_xor(v.x, m, 64));
        v.y = fmaxf(v.y, __shfl_xor(v.y, m, 64));
        v.z = fmaxf(v.z, __shfl_xor(v.z, m, 64));
        v.w = fmaxf(v.w, __shfl_xor(v.w, m, 64));
    }
    int wid = threadIdx.x >> 6, lane = threadIdx.x & 63;
    if (lane == 0) lds[wid] = v;
    __syncthreads();
    float4 r = lds[0];
    #pragma unroll
    for (int w = 1; w < 4; ++w) {
        float4 o = lds[w];
        r.x = fmaxf(r.x, o.x); r.y = fmaxf(r.y, o.y);
        r.z = fmaxf(r.z, o.z); r.w = fmaxf(r.w, o.w);
    }
    __syncthreads();
    return r;
}

__device__ inline float4 blockSum4(float4 v, float4* lds) {
    #pragma unroll
    for (int m = 32; m >= 1; m >>= 1) {
        v.x += __shfl_xor(v.x, m, 64);
        v.y += __shfl_xor(v.y, m, 64);
        v.z += __shfl_xor(v.z, m, 64);
        v.w += __shfl_xor(v.w, m, 64);
    }
    int wid = threadIdx.x >> 6, lane = threadIdx.x & 63;
    if (lane == 0) lds[wid] = v;
    __syncthreads();
    float4 r = lds[0];
    #pragma unroll
    for (int w = 1; w < 4; ++w) {
        float4 o = lds[w];
        r.x += o.x; r.y += o.y; r.z += o.z; r.w += o.w;
    }
    __syncthreads();
    return r;
}

// ---------------------------------------------------------------------------
// Kernel 2: segment softmax folded into per-node scalar weight:
//   wbar[i] = (1/HEADS) * sum_h exp(scores[i,h]-m[g,h]) / Z[g,h]
// ---------------------------------------------------------------------------
__global__ __launch_bounds__(256)
void segsoftmax_kernel(const float* __restrict__ scores, const int* __restrict__ batch,
                       float* __restrict__ wbar, int N)
{
    const int g = blockIdx.x;
    const int tid = threadIdx.x;
    __shared__ int sB[2];
    __shared__ float4 sRed[4];

    if (tid < 2) {
        int target = g + tid, lo = 0, hi = N;
        while (lo < hi) { int mid = (lo + hi) >> 1; if (batch[mid] < target) lo = mid + 1; else hi = mid; }
        sB[tid] = lo;
    }
    __syncthreads();
    const int start = sB[0], end = sB[1];

    float4 mv = make_float4(-INFINITY, -INFINITY, -INFINITY, -INFINITY);
    for (int i = start + tid; i < end; i += 256) {
        float4 s = *(const float4*)(scores + (size_t)i * HEADS);
        mv.x = fmaxf(mv.x, s.x); mv.y = fmaxf(mv.y, s.y);
        mv.z = fmaxf(mv.z, s.z); mv.w = fmaxf(mv.w, s.w);
    }
    mv = blockMax4(mv, sRed);

    float4 sv = make_float4(0.f, 0.f, 0.f, 0.f);
    for (int i = start + tid; i < end; i += 256) {
        float4 s = *(const float4*)(scores + (size_t)i * HEADS);
        sv.x += expf(s.x - mv.x); sv.y += expf(s.y - mv.y);
        sv.z += expf(s.z - mv.z); sv.w += expf(s.w - mv.w);
    }
    sv = blockSum4(sv, sRed);
    float4 rz;
    rz.x = sv.x > 0.f ? 1.f / sv.x : 0.f;
    rz.y = sv.y > 0.f ? 1.f / sv.y : 0.f;
    rz.z = sv.z > 0.f ? 1.f / sv.z : 0.f;
    rz.w = sv.w > 0.f ? 1.f / sv.w : 0.f;

    for (int i = start + tid; i < end; i += 256) {
        float4 s = *(const float4*)(scores + (size_t)i * HEADS);
        float w = expf(s.x - mv.x) * rz.x + expf(s.y - mv.y) * rz.y +
                  expf(s.z - mv.z) * rz.z + expf(s.w - mv.w) * rz.w;
        wbar[i] = 0.25f * w;
    }
}

// ---------------------------------------------------------------------------
// Kernel 3: partial[g,s,c] = sum over segment-g nodes (strided by S_SPLIT)
// of wbar[i]*x[i,c]. Grid (G, S_SPLIT) -> 2048 blocks (8/CU, 32 waves/CU).
// Per wave: one node per iter, 16B/lane float4 coalesced loads.
// ---------------------------------------------------------------------------
__global__ __launch_bounds__(256)
void pool_partial_kernel(const float* __restrict__ x, const float* __restrict__ wbar,
                         const int* __restrict__ batch, float* __restrict__ partial, int N)
{
    const int g = blockIdx.x;
    const int s = blockIdx.y;
    const int tid = threadIdx.x;
    const int lane = tid & 63;   // float4 channel index (64*16B = 1KB row)
    const int rg   = tid >> 6;   // wave id 0..3
    __shared__ int sB[2];
    __shared__ float4 red[4][64];

    if (tid < 2) {
        int target = g + tid, lo = 0, hi = N;
        while (lo < hi) { int mid = (lo + hi) >> 1; if (batch[mid] < target) lo = mid + 1; else hi = mid; }
        sB[tid] = lo;
    }
    __syncthreads();
    const int start = sB[0], end = sB[1];

    const float4* x4 = (const float4*)x;
    float4 a = make_float4(0.f, 0.f, 0.f, 0.f);
    const int stride = S_SPLIT * 4;
    #pragma unroll 2
    for (int n = start + s + S_SPLIT * rg; n < end; n += stride) {
        float w = wbar[n];                       // wave-uniform broadcast load
        float4 v = x4[(size_t)n * (H / 4) + lane];
        a.x = fmaf(w, v.x, a.x); a.y = fmaf(w, v.y, a.y);
        a.z = fmaf(w, v.z, a.z); a.w = fmaf(w, v.w, a.w);
    }

    red[rg][lane] = a;
    __syncthreads();
    if (tid < 64) {
        float4 r0 = red[0][tid], r1 = red[1][tid], r2 = red[2][tid], r3 = red[3][tid];
        float4 o;
        o.x = (r0.x + r1.x) + (r2.x + r3.x);
        o.y = (r0.y + r1.y) + (r2.y + r3.y);
        o.z = (r0.z + r1.z) + (r2.z + r3.z);
        o.w = (r0.w + r1.w) + (r2.w + r3.w);
        ((float4*)partial)[((size_t)g * S_SPLIT + s) * (H / 4) + tid] = o;
    }
}

// ---------------------------------------------------------------------------
// Kernel 4: out[g,c] = sum_s partial[g,s,c]  (tiny, 2.5MB traffic)
// ---------------------------------------------------------------------------
__global__ __launch_bounds__(64)
void pool_reduce_kernel(const float* __restrict__ partial, float* __restrict__ out)
{
    const int g = blockIdx.x;
    const int t = threadIdx.x;
    const float4* p4 = (const float4*)partial;
    float4 a = p4[((size_t)g * S_SPLIT + 0) * (H / 4) + t];
    #pragma unroll
    for (int s = 1; s < S_SPLIT; ++s) {
        float4 b = p4[((size_t)g * S_SPLIT + s) * (H / 4) + t];
        a.x += b.x; a.y += b.y; a.z += b.z; a.w += b.w;
    }
    ((float4*)out)[(size_t)g * (H / 4) + t] = a;
}

// ---------------------------------------------------------------------------
extern "C" void kernel_launch(void* const* d_in, const int* in_sizes, int n_in,
                              void* d_out, int out_size, void* d_ws, size_t ws_size,
                              hipStream_t stream)
{
    const float* x     = (const float*)d_in[0];
    const int*   batch = (const int*)d_in[1];
    const float* W1    = (const float*)d_in[2];
    const float* b1    = (const float*)d_in[3];
    const float* W2    = (const float*)d_in[4];
    float*       out   = (float*)d_out;

    const int N = in_sizes[1];          // batch has N elements
    const int G = out_size / H;         // out is [G, H]

    // ws layout: scores [N*4] f32, wbar [N] f32 (~4 MB total).
    // partial [G*S*H] (2MB) ALIASES scores: scores is dead after k2.
    float* scores  = (float*)d_ws;
    float* wbar    = scores + (size_t)N * HEADS;
    float* partial = scores;            // reuse (stream-ordered, safe)

    scores_kernel<<<dim3((N + BM - 1) / BM), dim3(256), 0, stream>>>(x, W1, b1, W2, scores, N);
    segsoftmax_kernel<<<dim3(G), dim3(256), 0, stream>>>(scores, batch, wbar, N);
    pool_partial_kernel<<<dim3(G, S_SPLIT), dim3(256), 0, stream>>>(x, wbar, batch, partial, N);
    pool_reduce_kernel<<<dim3(G), dim3(64), 0, stream>>>(partial, out);
}

// Round 6
// 690.663 us; speedup vs baseline: 1.5049x; 1.5049x over previous
//
#include <hip/hip_runtime.h>
#include <math.h>

#define H 256
#define HEADS 4
#define BM 64
#define BK 32
#define TM 8
#define TN 8          // strided columns: thread tx owns cols tx + 32*c
#define S_SPLIT 4

// ---------------------------------------------------------------------------
// Kernel 1: scores[N,4] = tanh(x @ W1 + b1) @ W2   (fp32 vector-ALU path)
// Block 256 = tx(32) x ty(8). Thread tile: rows ty*8+0..7, cols tx+32c.
// Bank-conflict design (all LDS ops 2-way or better = free, per m136):
//  - sX stored as swizzled float4: quad (rq,k) at u = rq ^ ((k>>2)&7).
//    staging writes: bank = 4*((a>>2)^b) + (a&3), (a,b)=(tid>>3,tid&7)
//    -> 32 banks x 2 lanes. reads: 2-addr broadcast b128.
//  - sW read strided: wc[c]=sW[k][tx+32c] -> bank = tx%32, 2 lanes/bank.
//    (contiguous 8-col reads were the r4/r5 8-way conflict: 1.28e7 cycles)
// Register budget (r5 lesson: TM=16 spilled ~1GB to scratch):
//    acc 64 + ps 32 + xq 8 + wc 8 + misc ~= 90 VGPR, no spill at (256,2).
// ---------------------------------------------------------------------------
__global__ __launch_bounds__(256, 2)
void scores_kernel(const float* __restrict__ x, const float* __restrict__ W1,
                   const float* __restrict__ b1, const float* __restrict__ W2,
                   float* __restrict__ scores, int N)
{
    __shared__ float sX[BK * BM];     // swizzled float4 layout
    __shared__ float sW[BK][H];

    const int tid = threadIdx.x;
    const int tx = tid & 31;
    const int ty = tid >> 5;
    const int row0 = blockIdx.x * BM;

    float acc[TM][TN];
    #pragma unroll
    for (int r = 0; r < TM; ++r)
        #pragma unroll
        for (int c = 0; c < TN; ++c) acc[r][c] = 0.f;

    for (int k0 = 0; k0 < H; k0 += BK) {
        // stage x tile (64 rows x 32 k): 512 float4, 2/thread, swizzled write
        #pragma unroll
        for (int it = 0; it < 2; ++it) {
            int f  = it * 256 + tid;
            int r  = f >> 3;              // 0..63
            int kq = (f & 7) * 4;         // 0,4,..,28
            int row = row0 + r;
            float4 v = make_float4(0.f, 0.f, 0.f, 0.f);
            if (row < N) v = *(const float4*)(x + (size_t)row * H + k0 + kq);
            int u    = (r >> 2) ^ ((kq >> 2) & 7);   // (k>>2)==(kq>>2) for j<4
            int base = u * 4 + (r & 3);
            sX[(kq + 0) * BM + base] = v.x;
            sX[(kq + 1) * BM + base] = v.y;
            sX[(kq + 2) * BM + base] = v.z;
            sX[(kq + 3) * BM + base] = v.w;
        }
        // stage W1 tile (32 k-rows x 256 cols): 2048 float4, 8/thread
        #pragma unroll
        for (int it = 0; it < 8; ++it) {
            int f  = it * 256 + tid;
            int k  = f >> 6;
            int c4 = (f & 63) * 4;
            *(float4*)(&sW[k][c4]) = *(const float4*)(W1 + (size_t)(k0 + k) * H + c4);
        }
        __syncthreads();

        const float4* sX4 = (const float4*)sX;
        #pragma unroll
        for (int k = 0; k < BK; ++k) {
            const int swz = (k >> 2) & 7;
            float4 xq0 = sX4[k * (BM / 4) + ((ty * 2 + 0) ^ swz)];  // rows ty*8+0..3
            float4 xq1 = sX4[k * (BM / 4) + ((ty * 2 + 1) ^ swz)];  // rows ty*8+4..7
            float wc[TN];
            #pragma unroll
            for (int c = 0; c < TN; ++c) wc[c] = sW[k][tx + 32 * c]; // bank tx%32
            float xr[TM] = {xq0.x, xq0.y, xq0.z, xq0.w, xq1.x, xq1.y, xq1.z, xq1.w};
            #pragma unroll
            for (int r = 0; r < TM; ++r)
                #pragma unroll
                for (int c = 0; c < TN; ++c)
                    acc[r][c] = fmaf(xr[r], wc[c], acc[r][c]);
        }
        __syncthreads();
    }

    // epilogue: h = tanh(acc + b1[col]); ps[r][head] += h * W2[col][head]
    float ps[TM][HEADS];
    #pragma unroll
    for (int r = 0; r < TM; ++r)
        #pragma unroll
        for (int hh = 0; hh < HEADS; ++hh) ps[r][hh] = 0.f;

    #pragma unroll
    for (int c = 0; c < TN; ++c) {
        int col = tx + 32 * c;
        float bb = b1[col];
        float4 w2 = *(const float4*)(W2 + (size_t)col * HEADS);
        #pragma unroll
        for (int r = 0; r < TM; ++r) {
            float hv = tanhf(acc[r][c] + bb);
            ps[r][0] = fmaf(hv, w2.x, ps[r][0]);
            ps[r][1] = fmaf(hv, w2.y, ps[r][1]);
            ps[r][2] = fmaf(hv, w2.z, ps[r][2]);
            ps[r][3] = fmaf(hv, w2.w, ps[r][3]);
        }
    }
    // reduce across tx (xor<32 stays within each 32-lane half-wave)
    #pragma unroll
    for (int m = 16; m >= 1; m >>= 1) {
        #pragma unroll
        for (int r = 0; r < TM; ++r)
            #pragma unroll
            for (int hh = 0; hh < HEADS; ++hh)
                ps[r][hh] += __shfl_xor(ps[r][hh], m, 64);
    }
    if (tx == 0) {
        #pragma unroll
        for (int r = 0; r < TM; ++r) {
            int row = row0 + ty * TM + r;
            if (row < N) {
                float4 o = make_float4(ps[r][0], ps[r][1], ps[r][2], ps[r][3]);
                *(float4*)(scores + (size_t)row * HEADS) = o;
            }
        }
    }
}

// ---------------------------------------------------------------------------
// Block-wide float4 reductions (max / sum) for 256-thread blocks.
// ---------------------------------------------------------------------------
__device__ inline float4 blockMax4(float4 v, float4* lds) {
    #pragma unroll
    for (int m = 32; m >= 1; m >>= 1) {
        v.x = fmaxf(v.x, __shfl_xor(v.x, m, 64));
        v.y = fmaxf(v.y, __shfl_xor(v.y, m, 64));
        v.z = fmaxf(v.z, __shfl_xor(v.z, m, 64));
        v.w = fmaxf(v.w, __shfl_xor(v.w, m, 64));
    }
    int wid = threadIdx.x >> 6, lane = threadIdx.x & 63;
    if (lane == 0) lds[wid] = v;
    __syncthreads();
    float4 r = lds[0];
    #pragma unroll
    for (int w = 1; w < 4; ++w) {
        float4 o = lds[w];
        r.x = fmaxf(r.x, o.x); r.y = fmaxf(r.y, o.y);
        r.z = fmaxf(r.z, o.z); r.w = fmaxf(r.w, o.w);
    }
    __syncthreads();
    return r;
}

__device__ inline float4 blockSum4(float4 v, float4* lds) {
    #pragma unroll
    for (int m = 32; m >= 1; m >>= 1) {
        v.x += __shfl_xor(v.x, m, 64);
        v.y += __shfl_xor(v.y, m, 64);
        v.z += __shfl_xor(v.z, m, 64);
        v.w += __shfl_xor(v.w, m, 64);
    }
    int wid = threadIdx.x >> 6, lane = threadIdx.x & 63;
    if (lane == 0) lds[wid] = v;
    __syncthreads();
    float4 r = lds[0];
    #pragma unroll
    for (int w = 1; w < 4; ++w) {
        float4 o = lds[w];
        r.x += o.x; r.y += o.y; r.z += o.z; r.w += o.w;
    }
    __syncthreads();
    return r;
}

// ---------------------------------------------------------------------------
// Kernel 2: segment softmax folded into per-node scalar weight:
//   wbar[i] = (1/HEADS) * sum_h exp(scores[i,h]-m[g,h]) / Z[g,h]
// ---------------------------------------------------------------------------
__global__ __launch_bounds__(256)
void segsoftmax_kernel(const float* __restrict__ scores, const int* __restrict__ batch,
                       float* __restrict__ wbar, int N)
{
    const int g = blockIdx.x;
    const int tid = threadIdx.x;
    __shared__ int sB[2];
    __shared__ float4 sRed[4];

    if (tid < 2) {
        int target = g + tid, lo = 0, hi = N;
        while (lo < hi) { int mid = (lo + hi) >> 1; if (batch[mid] < target) lo = mid + 1; else hi = mid; }
        sB[tid] = lo;
    }
    __syncthreads();
    const int start = sB[0], end = sB[1];

    float4 mv = make_float4(-INFINITY, -INFINITY, -INFINITY, -INFINITY);
    for (int i = start + tid; i < end; i += 256) {
        float4 s = *(const float4*)(scores + (size_t)i * HEADS);
        mv.x = fmaxf(mv.x, s.x); mv.y = fmaxf(mv.y, s.y);
        mv.z = fmaxf(mv.z, s.z); mv.w = fmaxf(mv.w, s.w);
    }
    mv = blockMax4(mv, sRed);

    float4 sv = make_float4(0.f, 0.f, 0.f, 0.f);
    for (int i = start + tid; i < end; i += 256) {
        float4 s = *(const float4*)(scores + (size_t)i * HEADS);
        sv.x += expf(s.x - mv.x); sv.y += expf(s.y - mv.y);
        sv.z += expf(s.z - mv.z); sv.w += expf(s.w - mv.w);
    }
    sv = blockSum4(sv, sRed);
    float4 rz;
    rz.x = sv.x > 0.f ? 1.f / sv.x : 0.f;
    rz.y = sv.y > 0.f ? 1.f / sv.y : 0.f;
    rz.z = sv.z > 0.f ? 1.f / sv.z : 0.f;
    rz.w = sv.w > 0.f ? 1.f / sv.w : 0.f;

    for (int i = start + tid; i < end; i += 256) {
        float4 s = *(const float4*)(scores + (size_t)i * HEADS);
        float w = expf(s.x - mv.x) * rz.x + expf(s.y - mv.y) * rz.y +
                  expf(s.z - mv.z) * rz.z + expf(s.w - mv.w) * rz.w;
        wbar[i] = 0.25f * w;
    }
}

// ---------------------------------------------------------------------------
// Kernel 3: partial[g,s,c] = sum over segment-g nodes (strided by S_SPLIT)
// of wbar[i]*x[i,c]. Grid (G, S_SPLIT) -> 2048 blocks, 32 waves/CU.
// ---------------------------------------------------------------------------
__global__ __launch_bounds__(256)
void pool_partial_kernel(const float* __restrict__ x, const float* __restrict__ wbar,
                         const int* __restrict__ batch, float* __restrict__ partial, int N)
{
    const int g = blockIdx.x;
    const int s = blockIdx.y;
    const int tid = threadIdx.x;
    const int lane = tid & 63;
    const int rg   = tid >> 6;
    __shared__ int sB[2];
    __shared__ float4 red[4][64];

    if (tid < 2) {
        int target = g + tid, lo = 0, hi = N;
        while (lo < hi) { int mid = (lo + hi) >> 1; if (batch[mid] < target) lo = mid + 1; else hi = mid; }
        sB[tid] = lo;
    }
    __syncthreads();
    const int start = sB[0], end = sB[1];

    const float4* x4 = (const float4*)x;
    float4 a = make_float4(0.f, 0.f, 0.f, 0.f);
    const int stride = S_SPLIT * 4;
    #pragma unroll 2
    for (int n = start + s + S_SPLIT * rg; n < end; n += stride) {
        float w = wbar[n];
        float4 v = x4[(size_t)n * (H / 4) + lane];
        a.x = fmaf(w, v.x, a.x); a.y = fmaf(w, v.y, a.y);
        a.z = fmaf(w, v.z, a.z); a.w = fmaf(w, v.w, a.w);
    }

    red[rg][lane] = a;
    __syncthreads();
    if (tid < 64) {
        float4 r0 = red[0][tid], r1 = red[1][tid], r2 = red[2][tid], r3 = red[3][tid];
        float4 o;
        o.x = (r0.x + r1.x) + (r2.x + r3.x);
        o.y = (r0.y + r1.y) + (r2.y + r3.y);
        o.z = (r0.z + r1.z) + (r2.z + r3.z);
        o.w = (r0.w + r1.w) + (r2.w + r3.w);
        ((float4*)partial)[((size_t)g * S_SPLIT + s) * (H / 4) + tid] = o;
    }
}

// ---------------------------------------------------------------------------
// Kernel 4: out[g,c] = sum_s partial[g,s,c]
// ---------------------------------------------------------------------------
__global__ __launch_bounds__(64)
void pool_reduce_kernel(const float* __restrict__ partial, float* __restrict__ out)
{
    const int g = blockIdx.x;
    const int t = threadIdx.x;
    const float4* p4 = (const float4*)partial;
    float4 a = p4[((size_t)g * S_SPLIT + 0) * (H / 4) + t];
    #pragma unroll
    for (int s = 1; s < S_SPLIT; ++s) {
        float4 b = p4[((size_t)g * S_SPLIT + s) * (H / 4) + t];
        a.x += b.x; a.y += b.y; a.z += b.z; a.w += b.w;
    }
    ((float4*)out)[(size_t)g * (H / 4) + t] = a;
}

// ---------------------------------------------------------------------------
extern "C" void kernel_launch(void* const* d_in, const int* in_sizes, int n_in,
                              void* d_out, int out_size, void* d_ws, size_t ws_size,
                              hipStream_t stream)
{
    const float* x     = (const float*)d_in[0];
    const int*   batch = (const int*)d_in[1];
    const float* W1    = (const float*)d_in[2];
    const float* b1    = (const float*)d_in[3];
    const float* W2    = (const float*)d_in[4];
    float*       out   = (float*)d_out;

    const int N = in_sizes[1];
    const int G = out_size / H;

    // ws: scores [N*4] f32, wbar [N] f32; partial aliases scores (dead after k2)
    float* scores  = (float*)d_ws;
    float* wbar    = scores + (size_t)N * HEADS;
    float* partial = scores;

    scores_kernel<<<dim3((N + BM - 1) / BM), dim3(256), 0, stream>>>(x, W1, b1, W2, scores, N);
    segsoftmax_kernel<<<dim3(G), dim3(256), 0, stream>>>(scores, batch, wbar, N);
    pool_partial_kernel<<<dim3(G, S_SPLIT), dim3(256), 0, stream>>>(x, wbar, batch, partial, N);
    pool_reduce_kernel<<<dim3(G), dim3(64), 0, stream>>>(partial, out);
}

// Round 8
// 410.062 us; speedup vs baseline: 2.5347x; 1.6843x over previous
//
#include <hip/hip_runtime.h>
#include <math.h>

#define H 256
#define HEADS 4
#define BM 64          // rows per block (k1)
#define S_SPLIT 4

typedef _Float16 f16;
typedef f16  f16x4 __attribute__((ext_vector_type(4)));
typedef f16  f16x8 __attribute__((ext_vector_type(8)));
typedef float f32x4 __attribute__((ext_vector_type(4)));

// ---------------------------------------------------------------------------
// Prep: split W1 (fp32 [K=256][256]) into fp16 hi/lo, packed in the exact
// B-fragment layout of mfma_f32_16x16x32_f16:
//   W1p[ks(8)][hl(2)][ct(16)][lane(64)][j(8)],
//   element (k,col): ks=k>>5, ct=col>>4, lane=(col&15)+16*((k&31)>>3), j=k&7
// so the GEMM's B frag read is a linear lane*16B ds_read_b128. 256KB total,
// L2/L3-resident. Runs once per launch (~µs).
// ---------------------------------------------------------------------------
__global__ __launch_bounds__(256)
void prep_w1_kernel(const float* __restrict__ W1, f16* __restrict__ W1p)
{
    const int k   = blockIdx.x;     // 0..255 (K index = W1 row)
    const int col = threadIdx.x;    // 0..255
    float v = W1[(size_t)k * H + col];
    f16 h = (f16)v;
    f16 l = (f16)(v - (float)h);
    int ks   = k >> 5;
    int lane = (col & 15) + 16 * ((k & 31) >> 3);
    int j    = k & 7;
    int ct   = col >> 4;
    size_t offh = ((((size_t)ks * 2 + 0) * 16 + ct) * 64 + lane) * 8 + j;
    size_t offl = ((((size_t)ks * 2 + 1) * 16 + ct) * 64 + lane) * 8 + j;
    W1p[offh] = h;
    W1p[offl] = l;
}

// ---------------------------------------------------------------------------
// Kernel 1: scores[N,4] = tanh(x @ W1 + b1) @ W2 via split-fp16 MFMA.
//   x = xh + xl (fp16 split, in-kernel), acc = xh@Wh + xh@Wl + xl@Wh  (fp32)
//   dropped xl@Wl ~ 2^-22 relative -> fp32-grade accuracy.
// Block: 256 thr = 4 waves; tile 64 rows x 256 cols (full N -> x read ONCE).
// Wave w owns cols w*64..+63 = 4 col-tiles; acc = 4x4 tiles of 16x16 (f32x4).
// K-loop: 8 steps of 32. A staged fp32->h/l into frag layout (slot==lane!),
// B copied from pre-packed W1p. All frag reads: linear lane*16B b128
// (conflict-free 2-way). MFMA C/D layout per m89: col=l&15, row=(l>>4)*4+reg.
// Epilogue: tanh + W2 fold, 16-lane shfl_xor col-reduce, LDS cross-wave.
// VGPR budget ~160 (acc 64 + frags 64 + staging) -> no spill at (256,2).
// LDS 40KB -> 2 blocks/CU.
// ---------------------------------------------------------------------------
__global__ __launch_bounds__(256, 2)
void scores_mfma_kernel(const float* __restrict__ x, const f16* __restrict__ W1p,
                        const float* __restrict__ b1, const float* __restrict__ W2,
                        float* __restrict__ scores, int N)
{
    __shared__ f16 A_lds[2 * 4 * 64 * 8];     // [hl][rt][lane][8]  = 8KB
    __shared__ f16 B_lds[2 * 16 * 64 * 8];    // [hl][ct][lane][8]  = 32KB

    const int tid  = threadIdx.x;
    const int w    = tid >> 6;
    const int l    = tid & 63;
    const int row0 = blockIdx.x * BM;

    f32x4 acc[4][4];
    #pragma unroll
    for (int rt = 0; rt < 4; ++rt)
        #pragma unroll
        for (int c = 0; c < 4; ++c) acc[rt][c] = (f32x4){0.f, 0.f, 0.f, 0.f};

    for (int ks = 0; ks < 8; ++ks) {
        // ---- stage A: x[64 rows][32 k] fp32 -> hi/lo fp16, frag-packed.
        // thread -> (r = f>>3, kq = (f&7)*4); dest slot = (r&15)+16*(kq>>3),
        // j0 = kq&7 in {0,4}: two 8B ds_write_b64 per float4 (hi, lo).
        #pragma unroll
        for (int it = 0; it < 2; ++it) {
            int f  = it * 256 + tid;
            int r  = f >> 3;
            int kq = (f & 7) * 4;
            float4 v = make_float4(0.f, 0.f, 0.f, 0.f);
            if (row0 + r < N)
                v = *(const float4*)(x + (size_t)(row0 + r) * H + ks * 32 + kq);
            f16 h0 = (f16)v.x, h1 = (f16)v.y, h2 = (f16)v.z, h3 = (f16)v.w;
            f16x4 hv = {h0, h1, h2, h3};
            f16x4 lv = {(f16)(v.x - (float)h0), (f16)(v.y - (float)h1),
                        (f16)(v.z - (float)h2), (f16)(v.w - (float)h3)};
            int slot = (r & 15) + 16 * (kq >> 3);
            int rt   = r >> 4;
            int j0   = kq & 7;
            *(f16x4*)&A_lds[(((0 * 4 + rt) * 64) + slot) * 8 + j0] = hv;
            *(f16x4*)&A_lds[(((1 * 4 + rt) * 64) + slot) * 8 + j0] = lv;
        }
        // ---- stage B: linear 32KB copy of W1p chunk ks (already frag-packed)
        {
            const float4* src = (const float4*)(W1p + (size_t)ks * (2 * 16 * 64 * 8));
            float4* dst = (float4*)B_lds;
            #pragma unroll
            for (int i = 0; i < 8; ++i)
                dst[i * 256 + tid] = src[i * 256 + tid];
        }
        __syncthreads();

        // ---- fragments: linear lane*16B b128 reads
        f16x8 af[2][4], bf[2][4];
        #pragma unroll
        for (int rt = 0; rt < 4; ++rt) {
            af[0][rt] = *(const f16x8*)&A_lds[((0 * 4 + rt) * 64 + l) * 8];
            af[1][rt] = *(const f16x8*)&A_lds[((1 * 4 + rt) * 64 + l) * 8];
        }
        #pragma unroll
        for (int c = 0; c < 4; ++c) {
            int ct = w * 4 + c;
            bf[0][c] = *(const f16x8*)&B_lds[((0 * 16 + ct) * 64 + l) * 8];
            bf[1][c] = *(const f16x8*)&B_lds[((1 * 16 + ct) * 64 + l) * 8];
        }
        // ---- 48 MFMA: 16 tiles x 3 products, fp32 accumulate
        #pragma unroll
        for (int rt = 0; rt < 4; ++rt)
            #pragma unroll
            for (int c = 0; c < 4; ++c) {
                f32x4 d = acc[rt][c];
                d = __builtin_amdgcn_mfma_f32_16x16x32_f16(af[0][rt], bf[0][c], d, 0, 0, 0);
                d = __builtin_amdgcn_mfma_f32_16x16x32_f16(af[0][rt], bf[1][c], d, 0, 0, 0);
                d = __builtin_amdgcn_mfma_f32_16x16x32_f16(af[1][rt], bf[0][c], d, 0, 0, 0);
                acc[rt][c] = d;
            }
        __syncthreads();
    }

    // ---- epilogue: h = tanh(acc + b1[col]); fold W2; reduce over cols.
    // lane's cols: col(c) = w*64 + c*16 + (l&15); rows: rt*16 + (l>>4)*4 + q.
    float  b1c[4];
    float4 w2c[4];
    #pragma unroll
    for (int c = 0; c < 4; ++c) {
        int col = w * 64 + c * 16 + (l & 15);
        b1c[c] = b1[col];
        w2c[c] = *(const float4*)(W2 + (size_t)col * HEADS);
    }
    float4* ps_lds = (float4*)A_lds;   // 4KB reuse; safe: frag reads done pre-barrier
    #pragma unroll
    for (int rt = 0; rt < 4; ++rt) {
        #pragma unroll
        for (int q = 0; q < 4; ++q) {
            float4 ps = make_float4(0.f, 0.f, 0.f, 0.f);
            #pragma unroll
            for (int c = 0; c < 4; ++c) {
                float hv = tanhf(acc[rt][c][q] + b1c[c]);
                ps.x = fmaf(hv, w2c[c].x, ps.x);
                ps.y = fmaf(hv, w2c[c].y, ps.y);
                ps.z = fmaf(hv, w2c[c].z, ps.z);
                ps.w = fmaf(hv, w2c[c].w, ps.w);
            }
            // reduce across the 16 lanes (l&15 = col-in-tile); xor<16 stays in group
            #pragma unroll
            for (int m = 8; m >= 1; m >>= 1) {
                ps.x += __shfl_xor(ps.x, m, 64);
                ps.y += __shfl_xor(ps.y, m, 64);
                ps.z += __shfl_xor(ps.z, m, 64);
                ps.w += __shfl_xor(ps.w, m, 64);
            }
            if ((l & 15) == 0) {
                int rloc = rt * 16 + (l >> 4) * 4 + q;
                ps_lds[w * 64 + rloc] = ps;   // per-wave partial (64-col slice)
            }
        }
    }
    __syncthreads();
    if (tid < 64) {
        int row = row0 + tid;
        if (row < N) {
            float4 a = ps_lds[0 * 64 + tid], b = ps_lds[1 * 64 + tid];
            float4 c = ps_lds[2 * 64 + tid], d = ps_lds[3 * 64 + tid];
            float4 o;
            o.x = (a.x + b.x) + (c.x + d.x);
            o.y = (a.y + b.y) + (c.y + d.y);
            o.z = (a.z + b.z) + (c.z + d.z);
            o.w = (a.w + b.w) + (c.w + d.w);
            *(float4*)(scores + (size_t)row * HEADS) = o;
        }
    }
}

// ---------------------------------------------------------------------------
// Block-wide float4 reductions (max / sum) for 256-thread blocks.
// ---------------------------------------------------------------------------
__device__ inline float4 blockMax4(float4 v, float4* lds) {
    #pragma unroll
    for (int m = 32; m >= 1; m >>= 1) {
        v.x = fmaxf(v.x, __shfl_xor(v.x, m, 64));
        v.y = fmaxf(v.y, __shfl_xor(v.y, m, 64));
        v.z = fmaxf(v.z, __shfl_xor(v.z, m, 64));
        v.w = fmaxf(v.w, __shfl_xor(v.w, m, 64));
    }
    int wid = threadIdx.x >> 6, lane = threadIdx.x & 63;
    if (lane == 0) lds[wid] = v;
    __syncthreads();
    float4 r = lds[0];
    #pragma unroll
    for (int w = 1; w < 4; ++w) {
        float4 o = lds[w];
        r.x = fmaxf(r.x, o.x); r.y = fmaxf(r.y, o.y);
        r.z = fmaxf(r.z, o.z); r.w = fmaxf(r.w, o.w);
    }
    __syncthreads();
    return r;
}

__device__ inline float4 blockSum4(float4 v, float4* lds) {
    #pragma unroll
    for (int m = 32; m >= 1; m >>= 1) {
        v.x += __shfl_xor(v.x, m, 64);
        v.y += __shfl_xor(v.y, m, 64);
        v.z += __shfl_xor(v.z, m, 64);
        v.w += __shfl_xor(v.w, m, 64);
    }
    int wid = threadIdx.x >> 6, lane = threadIdx.x & 63;
    if (lane == 0) lds[wid] = v;
    __syncthreads();
    float4 r = lds[0];
    #pragma unroll
    for (int w = 1; w < 4; ++w) {
        float4 o = lds[w];
        r.x += o.x; r.y += o.y; r.z += o.z; r.w += o.w;
    }
    __syncthreads();
    return r;
}

// ---------------------------------------------------------------------------
// Kernel 2: segment softmax folded into per-node scalar weight:
//   wbar[i] = (1/HEADS) * sum_h exp(scores[i,h]-m[g,h]) / Z[g,h]
// ---------------------------------------------------------------------------
__global__ __launch_bounds__(256)
void segsoftmax_kernel(const float* __restrict__ scores, const int* __restrict__ batch,
                       float* __restrict__ wbar, int N)
{
    const int g = blockIdx.x;
    const int tid = threadIdx.x;
    __shared__ int sB[2];
    __shared__ float4 sRed[4];

    if (tid < 2) {
        int target = g + tid, lo = 0, hi = N;
        while (lo < hi) { int mid = (lo + hi) >> 1; if (batch[mid] < target) lo = mid + 1; else hi = mid; }
        sB[tid] = lo;
    }
    __syncthreads();
    const int start = sB[0], end = sB[1];

    float4 mv = make_float4(-INFINITY, -INFINITY, -INFINITY, -INFINITY);
    for (int i = start + tid; i < end; i += 256) {
        float4 s = *(const float4*)(scores + (size_t)i * HEADS);
        mv.x = fmaxf(mv.x, s.x); mv.y = fmaxf(mv.y, s.y);
        mv.z = fmaxf(mv.z, s.z); mv.w = fmaxf(mv.w, s.w);
    }
    mv = blockMax4(mv, sRed);

    float4 sv = make_float4(0.f, 0.f, 0.f, 0.f);
    for (int i = start + tid; i < end; i += 256) {
        float4 s = *(const float4*)(scores + (size_t)i * HEADS);
        sv.x += expf(s.x - mv.x); sv.y += expf(s.y - mv.y);
        sv.z += expf(s.z - mv.z); sv.w += expf(s.w - mv.w);
    }
    sv = blockSum4(sv, sRed);
    float4 rz;
    rz.x = sv.x > 0.f ? 1.f / sv.x : 0.f;
    rz.y = sv.y > 0.f ? 1.f / sv.y : 0.f;
    rz.z = sv.z > 0.f ? 1.f / sv.z : 0.f;
    rz.w = sv.w > 0.f ? 1.f / sv.w : 0.f;

    for (int i = start + tid; i < end; i += 256) {
        float4 s = *(const float4*)(scores + (size_t)i * HEADS);
        float w = expf(s.x - mv.x) * rz.x + expf(s.y - mv.y) * rz.y +
                  expf(s.z - mv.z) * rz.z + expf(s.w - mv.w) * rz.w;
        wbar[i] = 0.25f * w;
    }
}

// ---------------------------------------------------------------------------
// Kernel 3: partial[g,s,c] = sum over segment-g nodes (strided by S_SPLIT)
// of wbar[i]*x[i,c]. Grid (G, S_SPLIT) -> 2048 blocks, 32 waves/CU.
// ---------------------------------------------------------------------------
__global__ __launch_bounds__(256)
void pool_partial_kernel(const float* __restrict__ x, const float* __restrict__ wbar,
                         const int* __restrict__ batch, float* __restrict__ partial, int N)
{
    const int g = blockIdx.x;
    const int s = blockIdx.y;
    const int tid = threadIdx.x;
    const int lane = tid & 63;
    const int rg   = tid >> 6;
    __shared__ int sB[2];
    __shared__ float4 red[4][64];

    if (tid < 2) {
        int target = g + tid, lo = 0, hi = N;
        while (lo < hi) { int mid = (lo + hi) >> 1; if (batch[mid] < target) lo = mid + 1; else hi = mid; }
        sB[tid] = lo;
    }
    __syncthreads();
    const int start = sB[0], end = sB[1];

    const float4* x4 = (const float4*)x;
    float4 a = make_float4(0.f, 0.f, 0.f, 0.f);
    const int stride = S_SPLIT * 4;
    #pragma unroll 2
    for (int n = start + s + S_SPLIT * rg; n < end; n += stride) {
        float w = wbar[n];
        float4 v = x4[(size_t)n * (H / 4) + lane];
        a.x = fmaf(w, v.x, a.x); a.y = fmaf(w, v.y, a.y);
        a.z = fmaf(w, v.z, a.z); a.w = fmaf(w, v.w, a.w);
    }

    red[rg][lane] = a;
    __syncthreads();
    if (tid < 64) {
        float4 r0 = red[0][tid], r1 = red[1][tid], r2 = red[2][tid], r3 = red[3][tid];
        float4 o;
        o.x = (r0.x + r1.x) + (r2.x + r3.x);
        o.y = (r0.y + r1.y) + (r2.y + r3.y);
        o.z = (r0.z + r1.z) + (r2.z + r3.z);
        o.w = (r0.w + r1.w) + (r2.w + r3.w);
        ((float4*)partial)[((size_t)g * S_SPLIT + s) * (H / 4) + tid] = o;
    }
}

// ---------------------------------------------------------------------------
// Kernel 4: out[g,c] = sum_s partial[g,s,c]
// ---------------------------------------------------------------------------
__global__ __launch_bounds__(64)
void pool_reduce_kernel(const float* __restrict__ partial, float* __restrict__ out)
{
    const int g = blockIdx.x;
    const int t = threadIdx.x;
    const float4* p4 = (const float4*)partial;
    float4 a = p4[((size_t)g * S_SPLIT + 0) * (H / 4) + t];
    #pragma unroll
    for (int s = 1; s < S_SPLIT; ++s) {
        float4 b = p4[((size_t)g * S_SPLIT + s) * (H / 4) + t];
        a.x += b.x; a.y += b.y; a.z += b.z; a.w += b.w;
    }
    ((float4*)out)[(size_t)g * (H / 4) + t] = a;
}

// ---------------------------------------------------------------------------
extern "C" void kernel_launch(void* const* d_in, const int* in_sizes, int n_in,
                              void* d_out, int out_size, void* d_ws, size_t ws_size,
                              hipStream_t stream)
{
    const float* x     = (const float*)d_in[0];
    const int*   batch = (const int*)d_in[1];
    const float* W1    = (const float*)d_in[2];
    const float* b1    = (const float*)d_in[3];
    const float* W2    = (const float*)d_in[4];
    float*       out   = (float*)d_out;

    const int N = in_sizes[1];
    const int G = out_size / H;

    // ws (4MB):
    //   [scores N*4 f32 | region2 N f32]
    //   region2 holds W1p (256KB, prep->k1) then wbar (800KB, k2->k3) --
    //   lifetimes disjoint (stream-serialized), aliasing safe. partial
    //   aliases scores (k3/k4 read wbar/partial only) -- safe.
    float* scores  = (float*)d_ws;
    float* region2 = scores + (size_t)N * HEADS;
    f16*   W1p     = (f16*)region2;
    float* wbar    = region2;
    float* partial = scores;

    prep_w1_kernel<<<dim3(H), dim3(H), 0, stream>>>(W1, W1p);
    scores_mfma_kernel<<<dim3((N + BM - 1) / BM), dim3(256), 0, stream>>>(x, W1p, b1, W2, scores, N);
    segsoftmax_kernel<<<dim3(G), dim3(256), 0, stream>>>(scores, batch, wbar, N);
    pool_partial_kernel<<<dim3(G, S_SPLIT), dim3(256), 0, stream>>>(x, wbar, batch, partial, N);
    pool_reduce_kernel<<<dim3(G), dim3(64), 0, stream>>>(partial, out);
}